// Round 1
// baseline (1309.039 us; speedup 1.0000x reference)
//
#include <hip/hip_runtime.h>
#include <math.h>

// GCN: 2x GCNConv (symmetric norm, self-loops) + ReLU + log_softmax
// Key identity: norm_e = dinv[src]*dinv[dst] factorizes; pre-scale rows by
// dinv at source, scatter raw, post-scale by dinv at destination.

constexpr int N  = 100000;
constexpr int E  = 3200000;
constexpr int F_IN = 128;
constexpr int H  = 50;
constexpr int C  = 2;

// ws layout (float offsets)
constexpr long DEG_OFF  = 0;                       // N     (deg then dinv in place)
constexpr long H1_OFF   = N;                       // N*H   h1' = dinv*(x@W1)
constexpr long AGG1_OFF = H1_OFF + (long)N * H;    // N*H   scatter target
constexpr long H2_OFF   = AGG1_OFF + (long)N * H;  // N*C   h2' = dinv*(z1@W2)
constexpr long AGG2_OFF = H2_OFF + (long)N * C;    // N*C
constexpr long WS_FLOATS = AGG2_OFF + (long)N * C; // = N*105 = 10.5M floats = 42 MB

__global__ __launch_bounds__(256) void k_init(float* __restrict__ ws) {
    long stride = (long)gridDim.x * blockDim.x;
    for (long i = (long)blockIdx.x * blockDim.x + threadIdx.x; i < WS_FLOATS; i += stride)
        ws[i] = (i < N) ? 1.0f : 0.0f;   // deg starts at 1 (self-loop); aggs at 0
}

__global__ __launch_bounds__(256) void k_deg(const int* __restrict__ dst,
                                             float* __restrict__ deg) {
    long stride = (long)gridDim.x * blockDim.x;
    for (long e = (long)blockIdx.x * blockDim.x + threadIdx.x; e < E; e += stride)
        atomicAdd(&deg[dst[e]], 1.0f);
}

__global__ __launch_bounds__(256) void k_dinv(float* __restrict__ deg) {
    int i = blockIdx.x * blockDim.x + threadIdx.x;
    if (i < N) deg[i] = rsqrtf(deg[i]);   // deg >= 1 always (self-loop)
}

// h1[i][j] = dinv[i] * sum_k x[i][k] * W1[k][j]
__global__ __launch_bounds__(256) void k_gemm1(const float* __restrict__ x,
                                               const float* __restrict__ W1,
                                               const float* __restrict__ dinv,
                                               float* __restrict__ h1) {
    __shared__ float xs[64][F_IN];   // 32 KB
    __shared__ float Ws[F_IN][H];    // 25.6 KB
    const int t = threadIdx.x;
    const int row0 = blockIdx.x * 64;

    for (int i = t; i < F_IN * H; i += 256)
        Ws[i / H][i % H] = W1[i];
    for (int i = t; i < 64 * F_IN; i += 256) {
        int r = i >> 7, c = i & 127;
        int gr = row0 + r;
        xs[r][c] = (gr < N) ? x[(long)gr * F_IN + c] : 0.0f;
    }
    __syncthreads();

    for (int lin = t; lin < 64 * H; lin += 256) {
        int r = lin / H, j = lin % H;
        int gr = row0 + r;
        if (gr >= N) continue;
        float acc = 0.0f;
        #pragma unroll 8
        for (int k = 0; k < F_IN; ++k)
            acc += xs[r][k] * Ws[k][j];
        h1[(long)gr * H + j] = dinv[gr] * acc;
    }
}

// wave-per-edge scatter: lanes 0..49 move one feature each
__global__ __launch_bounds__(256) void k_scatter1(const int* __restrict__ src,
                                                  const int* __restrict__ dst,
                                                  const float* __restrict__ h1,
                                                  float* __restrict__ agg1) {
    const int lane = threadIdx.x & 63;
    long gw = ((long)blockIdx.x * blockDim.x + threadIdx.x) >> 6;
    long nw = ((long)gridDim.x * blockDim.x) >> 6;
    for (long e = gw; e < E; e += nw) {
        int s = src[e];
        int d = dst[e];
        if (lane < H)
            atomicAdd(&agg1[(long)d * H + lane], h1[(long)s * H + lane]);
    }
}

// wave-per-node: z1 = relu(dinv*(agg1+h1)+b1); h2' = dinv * (z1 @ W2)
__global__ __launch_bounds__(256) void k_layer2(const float* __restrict__ agg1,
                                                const float* __restrict__ h1,
                                                const float* __restrict__ dinv,
                                                const float* __restrict__ b1,
                                                const float* __restrict__ W2,
                                                float* __restrict__ h2) {
    const int lane = threadIdx.x & 63;
    long gw = ((long)blockIdx.x * blockDim.x + threadIdx.x) >> 6;
    long nw = ((long)gridDim.x * blockDim.x) >> 6;
    for (long i = gw; i < N; i += nw) {
        float di = dinv[i];
        float p0 = 0.0f, p1 = 0.0f;
        if (lane < H) {
            float v = di * (agg1[i * H + lane] + h1[i * H + lane]) + b1[lane];
            v = fmaxf(v, 0.0f);
            p0 = v * W2[lane * 2 + 0];
            p1 = v * W2[lane * 2 + 1];
        }
        #pragma unroll
        for (int o = 32; o > 0; o >>= 1) {
            p0 += __shfl_xor(p0, o);
            p1 += __shfl_xor(p1, o);
        }
        if (lane == 0) {
            h2[i * 2 + 0] = di * p0;
            h2[i * 2 + 1] = di * p1;
        }
    }
}

__global__ __launch_bounds__(256) void k_scatter2(const int* __restrict__ src,
                                                  const int* __restrict__ dst,
                                                  const float* __restrict__ h2,
                                                  float* __restrict__ agg2) {
    long stride = (long)gridDim.x * blockDim.x;
    for (long e = (long)blockIdx.x * blockDim.x + threadIdx.x; e < E; e += stride) {
        int s = src[e];
        int d = dst[e];
        float v0 = h2[(long)s * 2 + 0];
        float v1 = h2[(long)s * 2 + 1];
        atomicAdd(&agg2[(long)d * 2 + 0], v0);
        atomicAdd(&agg2[(long)d * 2 + 1], v1);
    }
}

__global__ __launch_bounds__(256) void k_final(const float* __restrict__ agg2,
                                               const float* __restrict__ h2,
                                               const float* __restrict__ dinv,
                                               const float* __restrict__ b2,
                                               float* __restrict__ out) {
    int i = blockIdx.x * blockDim.x + threadIdx.x;
    if (i >= N) return;
    float di = dinv[i];
    float a0 = di * (agg2[i * 2 + 0] + h2[i * 2 + 0]) + b2[0];
    float a1 = di * (agg2[i * 2 + 1] + h2[i * 2 + 1]) + b2[1];
    float m = fmaxf(a0, a1);
    float lse = m + logf(expf(a0 - m) + expf(a1 - m));
    out[i * 2 + 0] = a0 - lse;
    out[i * 2 + 1] = a1 - lse;
}

extern "C" void kernel_launch(void* const* d_in, const int* in_sizes, int n_in,
                              void* d_out, int out_size, void* d_ws, size_t ws_size,
                              hipStream_t stream) {
    const float* x  = (const float*)d_in[0];
    const int*   ei = (const int*)d_in[1];   // [2][E]: row0 src, row1 dst
    const float* W1 = (const float*)d_in[2];
    const float* b1 = (const float*)d_in[3];
    const float* W2 = (const float*)d_in[4];
    const float* b2 = (const float*)d_in[5];
    float* out = (float*)d_out;
    float* ws  = (float*)d_ws;

    const int* src = ei;
    const int* dst = ei + E;
    float* deg  = ws + DEG_OFF;   // becomes dinv after k_dinv
    float* h1   = ws + H1_OFF;
    float* agg1 = ws + AGG1_OFF;
    float* h2   = ws + H2_OFF;
    float* agg2 = ws + AGG2_OFF;

    k_init<<<2048, 256, 0, stream>>>(ws);
    k_deg<<<2048, 256, 0, stream>>>(dst, deg);
    k_dinv<<<(N + 255) / 256, 256, 0, stream>>>(deg);
    k_gemm1<<<(N + 63) / 64, 256, 0, stream>>>(x, W1, deg, h1);
    k_scatter1<<<2048, 256, 0, stream>>>(src, dst, h1, agg1);
    k_layer2<<<2048, 256, 0, stream>>>(agg1, h1, deg, b1, W2, h2);
    k_scatter2<<<2048, 256, 0, stream>>>(src, dst, h2, agg2);
    k_final<<<(N + 255) / 256, 256, 0, stream>>>(agg2, h2, deg, b2, out);
}

// Round 2
// 723.437 us; speedup vs baseline: 1.8095x; 1.8095x over previous
//
#include <hip/hip_runtime.h>
#include <math.h>

// GCN 2-layer, CSR-gather formulation (no feature atomics).
// norm_e = dinv[src]*dinv[dst] factorizes: pre-scale rows at source (in the
// GEMM epilogue), gather-sum raw, post-scale at destination.
// CSR by dst is built once per call (histogram -> scan -> atomic-offset fill);
// fill order is nondeterministic but only perturbs fp sum order (~1e-3).

constexpr int N    = 100000;
constexpr int E    = 3200000;
constexpr int F_IN = 128;
constexpr int H    = 50;
constexpr int C    = 2;
constexpr int NB   = (N + 1023) / 1024;   // 98 scan blocks

// ---------------- CSR build ----------------

__global__ __launch_bounds__(256) void k_zero(int* __restrict__ degi) {
    int i = blockIdx.x * blockDim.x + threadIdx.x;
    if (i < N) degi[i] = 0;
}

__global__ __launch_bounds__(256) void k_deg(const int* __restrict__ dst,
                                             int* __restrict__ degi) {
    long stride = (long)gridDim.x * blockDim.x;
    for (long e = (long)blockIdx.x * blockDim.x + threadIdx.x; e < E; e += stride)
        atomicAdd(&degi[dst[e]], 1);
}

// Pass A: per-1024-chunk totals
__global__ __launch_bounds__(256) void k_blocksum(const int* __restrict__ degi,
                                                  int* __restrict__ bsum) {
    const int t = threadIdx.x, b = blockIdx.x;
    long i0 = (long)b * 1024 + t * 4;
    int s = 0;
    #pragma unroll
    for (int u = 0; u < 4; ++u) { long i = i0 + u; if (i < N) s += degi[i]; }
    // wave reduce
    #pragma unroll
    for (int o = 32; o > 0; o >>= 1) s += __shfl_xor(s, o);
    __shared__ int ws_[4];
    int lane = t & 63, wid = t >> 6;
    if (lane == 0) ws_[wid] = s;
    __syncthreads();
    if (t == 0) bsum[b] = ws_[0] + ws_[1] + ws_[2] + ws_[3];
}

// Pass B: exclusive scan of 98 block totals (single block)
__global__ __launch_bounds__(128) void k_scanbsum(const int* __restrict__ bsum,
                                                  int* __restrict__ boff) {
    const int t = threadIdx.x;
    __shared__ int tmp[128];
    int v = (t < NB) ? bsum[t] : 0;
    tmp[t] = v;
    __syncthreads();
    for (int o = 1; o < 128; o <<= 1) {
        int y = (t >= o) ? tmp[t - o] : 0;
        __syncthreads();
        tmp[t] += y;
        __syncthreads();
    }
    if (t < NB) boff[t] = tmp[t] - v;   // exclusive
}

// Pass C: final exclusive scan -> rowptr, fillcur
__global__ __launch_bounds__(256) void k_scanfinal(const int* __restrict__ degi,
                                                   const int* __restrict__ boff,
                                                   int* __restrict__ rowptr,
                                                   int* __restrict__ fillcur) {
    const int t = threadIdx.x, b = blockIdx.x;
    const int lane = t & 63, wid = t >> 6;
    long i0 = (long)b * 1024 + t * 4;
    int d[4];
    #pragma unroll
    for (int u = 0; u < 4; ++u) { long i = i0 + u; d[u] = (i < N) ? degi[i] : 0; }
    int tsum = d[0] + d[1] + d[2] + d[3];
    // inclusive wave scan
    int incl = tsum;
    #pragma unroll
    for (int o = 1; o < 64; o <<= 1) {
        int y = __shfl_up(incl, o);
        if (lane >= o) incl += y;
    }
    __shared__ int wsum[4];
    if (lane == 63) wsum[wid] = incl;
    __syncthreads();
    int wbase = 0;
    for (int w = 0; w < 4; ++w) if (w < wid) wbase += wsum[w];
    int base = boff[b] + wbase + (incl - tsum);
    int run = base;
    #pragma unroll
    for (int u = 0; u < 4; ++u) {
        long i = i0 + u;
        if (i < N) { rowptr[i] = run; fillcur[i] = run; }
        run += d[u];
    }
}

__global__ __launch_bounds__(256) void k_dinv(const int* __restrict__ degi,
                                              float* __restrict__ dinv) {
    int i = blockIdx.x * blockDim.x + threadIdx.x;
    if (i < N) dinv[i] = rsqrtf((float)degi[i] + 1.0f);   // +1 self loop
}

__global__ __launch_bounds__(256) void k_fill(const int* __restrict__ src,
                                              const int* __restrict__ dst,
                                              int* __restrict__ fillcur,
                                              int* __restrict__ colidx) {
    long stride = (long)gridDim.x * blockDim.x;
    for (long e = (long)blockIdx.x * blockDim.x + threadIdx.x; e < E; e += stride) {
        int pos = atomicAdd(&fillcur[dst[e]], 1);
        colidx[pos] = src[e];
    }
}

// ---------------- compute ----------------

// h1[i][j] = dinv[i] * sum_k x[i][k] * W1[k][j]   (register-tiled j)
__global__ __launch_bounds__(256) void k_gemm1(const float* __restrict__ x,
                                               const float* __restrict__ W1,
                                               const float* __restrict__ dinv,
                                               float* __restrict__ h1) {
    __shared__ float xs[64][F_IN];   // 32 KB
    __shared__ float Ws[F_IN][H];    // 25.6 KB
    const int t = threadIdx.x;
    const int row0 = blockIdx.x * 64;

    for (int i = t; i < F_IN * H; i += 256)
        Ws[i / H][i % H] = W1[i];
    for (int i = t; i < 64 * F_IN; i += 256) {
        int r = i >> 7, c = i & 127;
        int gr = row0 + r;
        xs[r][c] = (gr < N) ? x[(long)gr * F_IN + c] : 0.0f;
    }
    __syncthreads();

    const int r = t >> 2;          // 64 rows
    const int g = t & 3;           // 4 j-groups of 13 (covers 50)
    const int j0 = g * 13;
    int gr = row0 + r;
    if (gr >= N) return;
    float acc[13];
    #pragma unroll
    for (int u = 0; u < 13; ++u) acc[u] = 0.0f;
    #pragma unroll 4
    for (int k = 0; k < F_IN; ++k) {
        float xr = xs[r][k];
        #pragma unroll
        for (int u = 0; u < 13; ++u) {
            int j = j0 + u;
            if (j < H) acc[u] += xr * Ws[k][j];
        }
    }
    float di = dinv[gr];
    #pragma unroll
    for (int u = 0; u < 13; ++u) {
        int j = j0 + u;
        if (j < H) h1[(long)gr * H + j] = di * acc[u];
    }
}

// wave-per-node: agg1 = self + sum_{nbr} h1[nbr]; z1 = relu(di*agg1+b1);
// h2[i] = di * (z1 @ W2)
__global__ __launch_bounds__(256) void k_agg1_fused(const int* __restrict__ rowptr,
                                                    const int* __restrict__ degi,
                                                    const int* __restrict__ colidx,
                                                    const float* __restrict__ h1,
                                                    const float* __restrict__ dinv,
                                                    const float* __restrict__ b1,
                                                    const float* __restrict__ W2,
                                                    float* __restrict__ h2) {
    const int lane = threadIdx.x & 63;
    const bool act = lane < H;
    float b1v = act ? b1[lane] : 0.0f;
    float w20 = act ? W2[lane * 2 + 0] : 0.0f;
    float w21 = act ? W2[lane * 2 + 1] : 0.0f;

    long gw = ((long)blockIdx.x * blockDim.x + threadIdx.x) >> 6;
    long nw = ((long)gridDim.x * blockDim.x) >> 6;
    for (long i = gw; i < N; i += nw) {
        const int start = rowptr[i];
        const int deg   = degi[i];
        float a0 = act ? h1[i * (long)H + lane] : 0.0f;   // self loop
        float a1 = 0.0f, a2 = 0.0f, a3 = 0.0f;
        int k = 0;
        for (; k + 4 <= deg; k += 4) {
            int s0 = colidx[start + k + 0];
            int s1 = colidx[start + k + 1];
            int s2 = colidx[start + k + 2];
            int s3 = colidx[start + k + 3];
            if (act) {
                a0 += h1[(long)s0 * H + lane];
                a1 += h1[(long)s1 * H + lane];
                a2 += h1[(long)s2 * H + lane];
                a3 += h1[(long)s3 * H + lane];
            }
        }
        for (; k < deg; ++k) {
            int s = colidx[start + k];
            if (act) a0 += h1[(long)s * H + lane];
        }
        float agg = (a0 + a1) + (a2 + a3);
        float di = dinv[i];
        float v = fmaxf(di * agg + b1v, 0.0f);
        float p0 = v * w20, p1 = v * w21;
        #pragma unroll
        for (int o = 32; o > 0; o >>= 1) {
            p0 += __shfl_xor(p0, o);
            p1 += __shfl_xor(p1, o);
        }
        if (lane == 0) {
            h2[i * 2 + 0] = di * p0;
            h2[i * 2 + 1] = di * p1;
        }
    }
}

// wave-per-node, lanes over edges: out = log_softmax(di*(sum+self)+b2)
__global__ __launch_bounds__(256) void k_agg2_final(const int* __restrict__ rowptr,
                                                    const int* __restrict__ degi,
                                                    const int* __restrict__ colidx,
                                                    const float* __restrict__ h2,
                                                    const float* __restrict__ dinv,
                                                    const float* __restrict__ b2,
                                                    float* __restrict__ out) {
    const int lane = threadIdx.x & 63;
    long gw = ((long)blockIdx.x * blockDim.x + threadIdx.x) >> 6;
    long nw = ((long)gridDim.x * blockDim.x) >> 6;
    for (long i = gw; i < N; i += nw) {
        const int start = rowptr[i];
        const int deg   = degi[i];
        float s0 = 0.0f, s1 = 0.0f;
        for (int k = lane; k < deg; k += 64) {
            int s = colidx[start + k];
            s0 += h2[(long)s * 2 + 0];
            s1 += h2[(long)s * 2 + 1];
        }
        #pragma unroll
        for (int o = 32; o > 0; o >>= 1) {
            s0 += __shfl_xor(s0, o);
            s1 += __shfl_xor(s1, o);
        }
        if (lane == 0) {
            float di = dinv[i];
            float a0 = di * (s0 + h2[i * 2 + 0]) + b2[0];
            float a1 = di * (s1 + h2[i * 2 + 1]) + b2[1];
            float m = fmaxf(a0, a1);
            float lse = m + logf(expf(a0 - m) + expf(a1 - m));
            out[i * 2 + 0] = a0 - lse;
            out[i * 2 + 1] = a1 - lse;
        }
    }
}

extern "C" void kernel_launch(void* const* d_in, const int* in_sizes, int n_in,
                              void* d_out, int out_size, void* d_ws, size_t ws_size,
                              hipStream_t stream) {
    const float* x  = (const float*)d_in[0];
    const int*   ei = (const int*)d_in[1];   // [2][E]: row0 src, row1 dst
    const float* W1 = (const float*)d_in[2];
    const float* b1 = (const float*)d_in[3];
    const float* W2 = (const float*)d_in[4];
    const float* b2 = (const float*)d_in[5];
    float* out = (float*)d_out;

    const int* src = ei;
    const int* dst = ei + E;

    // ws layout
    int*   degi    = (int*)d_ws;            // N
    int*   rowptr  = degi + N;              // N
    int*   fillcur = rowptr + N;            // N
    int*   bsum    = fillcur + N;           // 128
    int*   boff    = bsum + 128;            // 128
    float* dinv    = (float*)(boff + 128);  // N
    int*   colidx  = (int*)(dinv + N);      // E
    float* h1      = (float*)(colidx + E);  // N*H
    float* h2      = h1 + (long)N * H;      // N*C   (~35 MB total)

    k_zero<<<(N + 255) / 256, 256, 0, stream>>>(degi);
    k_deg<<<2048, 256, 0, stream>>>(dst, degi);
    k_blocksum<<<NB, 256, 0, stream>>>(degi, bsum);
    k_scanbsum<<<1, 128, 0, stream>>>(bsum, boff);
    k_scanfinal<<<NB, 256, 0, stream>>>(degi, boff, rowptr, fillcur);
    k_dinv<<<(N + 255) / 256, 256, 0, stream>>>(degi, dinv);
    k_fill<<<2048, 256, 0, stream>>>(src, dst, fillcur, colidx);
    k_gemm1<<<(N + 63) / 64, 256, 0, stream>>>(x, W1, dinv, h1);
    k_agg1_fused<<<2048, 256, 0, stream>>>(rowptr, degi, colidx, h1, dinv, b1, W2, h2);
    k_agg2_final<<<2048, 256, 0, stream>>>(rowptr, degi, colidx, h2, dinv, b2, out);
}

// Round 3
// 574.078 us; speedup vs baseline: 2.2802x; 1.2602x over previous
//
#include <hip/hip_runtime.h>
#include <math.h>

// GCN 2-layer, CSR-gather formulation (no feature atomics).
// norm_e = dinv[src]*dinv[dst] factorizes: pre-scale rows at source (in the
// GEMM epilogue), gather-sum raw, post-scale at destination.
// CSR build: histogram -> scan -> atomic-offset fill, with dst-range
// partitioning (8 ranges ~ XCDs) so scatter writes stay in one L2 (R2 fix:
// was 15x write amplification = 196 MB HBM writes for 12.8 MB payload).

constexpr int N    = 100000;
constexpr int E    = 3200000;
constexpr int F_IN = 128;
constexpr int H    = 50;
constexpr int C    = 2;
constexpr int NB   = (N + 1023) / 1024;   // 98 scan blocks

constexpr int NRANGE = 8;                     // dst-space partitions (~XCDs)
constexpr int RSPAN  = (N + NRANGE - 1) / NRANGE;   // 12500 nodes/range
constexpr int NSLICE = 256;                   // edge slices per range
constexpr int ESLICE = (E + NSLICE - 1) / NSLICE;   // 12500 edges/slice

// ---------------- CSR build ----------------

__global__ __launch_bounds__(256) void k_zero(int* __restrict__ degi) {
    int i = blockIdx.x * blockDim.x + threadIdx.x;
    if (i < N) degi[i] = 0;
}

// range-partitioned histogram: block b -> dst range b%8, edge slice b/8
__global__ __launch_bounds__(256) void k_deg(const int* __restrict__ dst,
                                             int* __restrict__ degi) {
    const int r  = blockIdx.x % NRANGE;
    const int s  = blockIdx.x / NRANGE;
    const int lo = r * RSPAN, hi = min(N, lo + RSPAN);
    long e0 = (long)s * ESLICE;
    long e1 = min((long)E, e0 + ESLICE);
    for (long e = e0 + threadIdx.x; e < e1; e += 256) {
        int d = dst[e];
        if (d >= lo && d < hi) atomicAdd(&degi[d], 1);
    }
}

// Pass A: per-1024-chunk totals
__global__ __launch_bounds__(256) void k_blocksum(const int* __restrict__ degi,
                                                  int* __restrict__ bsum) {
    const int t = threadIdx.x, b = blockIdx.x;
    long i0 = (long)b * 1024 + t * 4;
    int s = 0;
    #pragma unroll
    for (int u = 0; u < 4; ++u) { long i = i0 + u; if (i < N) s += degi[i]; }
    #pragma unroll
    for (int o = 32; o > 0; o >>= 1) s += __shfl_xor(s, o);
    __shared__ int ws_[4];
    int lane = t & 63, wid = t >> 6;
    if (lane == 0) ws_[wid] = s;
    __syncthreads();
    if (t == 0) bsum[b] = ws_[0] + ws_[1] + ws_[2] + ws_[3];
}

// Pass B: exclusive scan of 98 block totals (single block)
__global__ __launch_bounds__(128) void k_scanbsum(const int* __restrict__ bsum,
                                                  int* __restrict__ boff) {
    const int t = threadIdx.x;
    __shared__ int tmp[128];
    int v = (t < NB) ? bsum[t] : 0;
    tmp[t] = v;
    __syncthreads();
    for (int o = 1; o < 128; o <<= 1) {
        int y = (t >= o) ? tmp[t - o] : 0;
        __syncthreads();
        tmp[t] += y;
        __syncthreads();
    }
    if (t < NB) boff[t] = tmp[t] - v;   // exclusive
}

// Pass C: final exclusive scan -> rowptr, fillcur
__global__ __launch_bounds__(256) void k_scanfinal(const int* __restrict__ degi,
                                                   const int* __restrict__ boff,
                                                   int* __restrict__ rowptr,
                                                   int* __restrict__ fillcur) {
    const int t = threadIdx.x, b = blockIdx.x;
    const int lane = t & 63, wid = t >> 6;
    long i0 = (long)b * 1024 + t * 4;
    int d[4];
    #pragma unroll
    for (int u = 0; u < 4; ++u) { long i = i0 + u; d[u] = (i < N) ? degi[i] : 0; }
    int tsum = d[0] + d[1] + d[2] + d[3];
    int incl = tsum;
    #pragma unroll
    for (int o = 1; o < 64; o <<= 1) {
        int y = __shfl_up(incl, o);
        if (lane >= o) incl += y;
    }
    __shared__ int wsum[4];
    if (lane == 63) wsum[wid] = incl;
    __syncthreads();
    int wbase = 0;
    for (int w = 0; w < 4; ++w) if (w < wid) wbase += wsum[w];
    int base = boff[b] + wbase + (incl - tsum);
    int run = base;
    #pragma unroll
    for (int u = 0; u < 4; ++u) {
        long i = i0 + u;
        if (i < N) { rowptr[i] = run; fillcur[i] = run; }
        run += d[u];
    }
}

__global__ __launch_bounds__(256) void k_dinv(const int* __restrict__ degi,
                                              float* __restrict__ dinv) {
    int i = blockIdx.x * blockDim.x + threadIdx.x;
    if (i < N) dinv[i] = rsqrtf((float)degi[i] + 1.0f);   // +1 self loop
}

// range-partitioned fill: writes to colidx confined to ~1.6 MB window per range
__global__ __launch_bounds__(256) void k_fill(const int* __restrict__ src,
                                              const int* __restrict__ dst,
                                              int* __restrict__ fillcur,
                                              int* __restrict__ colidx) {
    const int r  = blockIdx.x % NRANGE;
    const int s  = blockIdx.x / NRANGE;
    const int lo = r * RSPAN, hi = min(N, lo + RSPAN);
    long e0 = (long)s * ESLICE;
    long e1 = min((long)E, e0 + ESLICE);
    for (long e = e0 + threadIdx.x; e < e1; e += 256) {
        int d = dst[e];
        if (d >= lo && d < hi) {
            int pos = atomicAdd(&fillcur[d], 1);
            colidx[pos] = src[e];
        }
    }
}

// ---------------- compute ----------------

// h1[i][j] = dinv[i] * sum_k x[i][k] * W1[k][j]   (register-tiled j)
__global__ __launch_bounds__(256) void k_gemm1(const float* __restrict__ x,
                                               const float* __restrict__ W1,
                                               const float* __restrict__ dinv,
                                               float* __restrict__ h1) {
    __shared__ float xs[64][F_IN];   // 32 KB
    __shared__ float Ws[F_IN][H];    // 25.6 KB
    const int t = threadIdx.x;
    const int row0 = blockIdx.x * 64;

    for (int i = t; i < F_IN * H; i += 256)
        Ws[i / H][i % H] = W1[i];
    for (int i = t; i < 64 * F_IN; i += 256) {
        int r = i >> 7, c = i & 127;
        int gr = row0 + r;
        xs[r][c] = (gr < N) ? x[(long)gr * F_IN + c] : 0.0f;
    }
    __syncthreads();

    const int r = t >> 2;          // 64 rows
    const int g = t & 3;           // 4 j-groups of 13 (covers 50)
    const int j0 = g * 13;
    int gr = row0 + r;
    if (gr >= N) return;
    float acc[13];
    #pragma unroll
    for (int u = 0; u < 13; ++u) acc[u] = 0.0f;
    #pragma unroll 4
    for (int k = 0; k < F_IN; ++k) {
        float xr = xs[r][k];
        #pragma unroll
        for (int u = 0; u < 13; ++u) {
            int j = j0 + u;
            if (j < H) acc[u] += xr * Ws[k][j];
        }
    }
    float di = dinv[gr];
    #pragma unroll
    for (int u = 0; u < 13; ++u) {
        int j = j0 + u;
        if (j < H) h1[(long)gr * H + j] = di * acc[u];
    }
}

// wave-per-node: agg1 = self + sum_{nbr} h1[nbr]; z1 = relu(di*agg1+b1);
// h2[i] = di * (z1 @ W2)
__global__ __launch_bounds__(256) void k_agg1_fused(const int* __restrict__ rowptr,
                                                    const int* __restrict__ degi,
                                                    const int* __restrict__ colidx,
                                                    const float* __restrict__ h1,
                                                    const float* __restrict__ dinv,
                                                    const float* __restrict__ b1,
                                                    const float* __restrict__ W2,
                                                    float* __restrict__ h2) {
    const int lane = threadIdx.x & 63;
    const bool act = lane < H;
    float b1v = act ? b1[lane] : 0.0f;
    float w20 = act ? W2[lane * 2 + 0] : 0.0f;
    float w21 = act ? W2[lane * 2 + 1] : 0.0f;

    long gw = ((long)blockIdx.x * blockDim.x + threadIdx.x) >> 6;
    long nw = ((long)gridDim.x * blockDim.x) >> 6;
    for (long i = gw; i < N; i += nw) {
        const int start = rowptr[i];
        const int deg   = degi[i];
        float a0 = act ? h1[i * (long)H + lane] : 0.0f;   // self loop
        float a1 = 0.0f, a2 = 0.0f, a3 = 0.0f;
        int k = 0;
        for (; k + 4 <= deg; k += 4) {
            int s0 = colidx[start + k + 0];
            int s1 = colidx[start + k + 1];
            int s2 = colidx[start + k + 2];
            int s3 = colidx[start + k + 3];
            if (act) {
                a0 += h1[(long)s0 * H + lane];
                a1 += h1[(long)s1 * H + lane];
                a2 += h1[(long)s2 * H + lane];
                a3 += h1[(long)s3 * H + lane];
            }
        }
        for (; k < deg; ++k) {
            int s = colidx[start + k];
            if (act) a0 += h1[(long)s * H + lane];
        }
        float agg = (a0 + a1) + (a2 + a3);
        float di = dinv[i];
        float v = fmaxf(di * agg + b1v, 0.0f);
        float p0 = v * w20, p1 = v * w21;
        #pragma unroll
        for (int o = 32; o > 0; o >>= 1) {
            p0 += __shfl_xor(p0, o);
            p1 += __shfl_xor(p1, o);
        }
        if (lane == 0) {
            h2[i * 2 + 0] = di * p0;
            h2[i * 2 + 1] = di * p1;
        }
    }
}

// wave-per-node, lanes over edges: out = log_softmax(di*(sum+self)+b2)
__global__ __launch_bounds__(256) void k_agg2_final(const int* __restrict__ rowptr,
                                                    const int* __restrict__ degi,
                                                    const int* __restrict__ colidx,
                                                    const float* __restrict__ h2,
                                                    const float* __restrict__ dinv,
                                                    const float* __restrict__ b2,
                                                    float* __restrict__ out) {
    const int lane = threadIdx.x & 63;
    long gw = ((long)blockIdx.x * blockDim.x + threadIdx.x) >> 6;
    long nw = ((long)gridDim.x * blockDim.x) >> 6;
    for (long i = gw; i < N; i += nw) {
        const int start = rowptr[i];
        const int deg   = degi[i];
        float s0 = 0.0f, s1 = 0.0f;
        for (int k = lane; k < deg; k += 64) {
            int s = colidx[start + k];
            s0 += h2[(long)s * 2 + 0];
            s1 += h2[(long)s * 2 + 1];
        }
        #pragma unroll
        for (int o = 32; o > 0; o >>= 1) {
            s0 += __shfl_xor(s0, o);
            s1 += __shfl_xor(s1, o);
        }
        if (lane == 0) {
            float di = dinv[i];
            float a0 = di * (s0 + h2[i * 2 + 0]) + b2[0];
            float a1 = di * (s1 + h2[i * 2 + 1]) + b2[1];
            float m = fmaxf(a0, a1);
            float lse = m + logf(expf(a0 - m) + expf(a1 - m));
            out[i * 2 + 0] = a0 - lse;
            out[i * 2 + 1] = a1 - lse;
        }
    }
}

extern "C" void kernel_launch(void* const* d_in, const int* in_sizes, int n_in,
                              void* d_out, int out_size, void* d_ws, size_t ws_size,
                              hipStream_t stream) {
    const float* x  = (const float*)d_in[0];
    const int*   ei = (const int*)d_in[1];   // [2][E]: row0 src, row1 dst
    const float* W1 = (const float*)d_in[2];
    const float* b1 = (const float*)d_in[3];
    const float* W2 = (const float*)d_in[4];
    const float* b2 = (const float*)d_in[5];
    float* out = (float*)d_out;

    const int* src = ei;
    const int* dst = ei + E;

    // ws layout
    int*   degi    = (int*)d_ws;            // N
    int*   rowptr  = degi + N;              // N
    int*   fillcur = rowptr + N;            // N
    int*   bsum    = fillcur + N;           // 128
    int*   boff    = bsum + 128;            // 128
    float* dinv    = (float*)(boff + 128);  // N
    int*   colidx  = (int*)(dinv + N);      // E
    float* h1      = (float*)(colidx + E);  // N*H
    float* h2      = h1 + (long)N * H;      // N*C   (~35 MB total)

    k_zero<<<(N + 255) / 256, 256, 0, stream>>>(degi);
    k_deg<<<NRANGE * NSLICE, 256, 0, stream>>>(dst, degi);
    k_blocksum<<<NB, 256, 0, stream>>>(degi, bsum);
    k_scanbsum<<<1, 128, 0, stream>>>(bsum, boff);
    k_scanfinal<<<NB, 256, 0, stream>>>(degi, boff, rowptr, fillcur);
    k_dinv<<<(N + 255) / 256, 256, 0, stream>>>(degi, dinv);
    k_fill<<<NRANGE * NSLICE, 256, 0, stream>>>(src, dst, fillcur, colidx);
    k_gemm1<<<(N + 63) / 64, 256, 0, stream>>>(x, W1, dinv, h1);
    k_agg1_fused<<<2048, 256, 0, stream>>>(rowptr, degi, colidx, h1, dinv, b1, W2, h2);
    k_agg2_final<<<2048, 256, 0, stream>>>(rowptr, degi, colidx, h2, dinv, b2, out);
}

// Round 4
// 506.392 us; speedup vs baseline: 2.5850x; 1.1337x over previous
//
#include <hip/hip_runtime.h>
#include <math.h>

// GCN 2-layer, CSR-gather formulation (no feature atomics).
// norm_e = dinv[src]*dinv[dst] factorizes: pre-scale rows at source (in the
// GEMM epilogue), gather-sum raw, post-scale at destination.
// CSR build: histogram -> scan -> atomic-offset fill, dst-range partitioned
// (R2 fix: scatter write amplification).
// R3 fix: gemm1 had 16-way LDS bank conflicts (xs stride 128) + scalar Ws
// reads -> pad xs stride to 132, Ws rows to 64, float4/b128 everywhere.

constexpr int N    = 100000;
constexpr int E    = 3200000;
constexpr int F_IN = 128;
constexpr int H    = 50;
constexpr int C    = 2;
constexpr int NB   = (N + 1023) / 1024;   // 98 scan blocks

constexpr int NRANGE = 8;                     // dst-space partitions (~XCDs)
constexpr int RSPAN  = (N + NRANGE - 1) / NRANGE;   // 12500 nodes/range
constexpr int NSLICE = 256;                   // edge slices per range
constexpr int ESLICE = (E + NSLICE - 1) / NSLICE;   // 12500 edges/slice

constexpr int XS_LD = F_IN + 4;   // 132: (4r+k)%32 -> worst 2-way (free)
constexpr int WS_LD = 64;         // padded j-dim, 16-aligned groups

// ---------------- CSR build ----------------

__global__ __launch_bounds__(256) void k_zero(int* __restrict__ degi) {
    int i = blockIdx.x * blockDim.x + threadIdx.x;
    if (i < N) degi[i] = 0;
}

// range-partitioned histogram: block b -> dst range b%8, edge slice b/8
__global__ __launch_bounds__(256) void k_deg(const int* __restrict__ dst,
                                             int* __restrict__ degi) {
    const int r  = blockIdx.x % NRANGE;
    const int s  = blockIdx.x / NRANGE;
    const int lo = r * RSPAN, hi = min(N, lo + RSPAN);
    long e0 = (long)s * ESLICE;
    long e1 = min((long)E, e0 + ESLICE);
    for (long e = e0 + threadIdx.x; e < e1; e += 256) {
        int d = dst[e];
        if (d >= lo && d < hi) atomicAdd(&degi[d], 1);
    }
}

// Pass A: per-1024-chunk totals
__global__ __launch_bounds__(256) void k_blocksum(const int* __restrict__ degi,
                                                  int* __restrict__ bsum) {
    const int t = threadIdx.x, b = blockIdx.x;
    long i0 = (long)b * 1024 + t * 4;
    int s = 0;
    #pragma unroll
    for (int u = 0; u < 4; ++u) { long i = i0 + u; if (i < N) s += degi[i]; }
    #pragma unroll
    for (int o = 32; o > 0; o >>= 1) s += __shfl_xor(s, o);
    __shared__ int ws_[4];
    int lane = t & 63, wid = t >> 6;
    if (lane == 0) ws_[wid] = s;
    __syncthreads();
    if (t == 0) bsum[b] = ws_[0] + ws_[1] + ws_[2] + ws_[3];
}

// Pass B: exclusive scan of 98 block totals (single block)
__global__ __launch_bounds__(128) void k_scanbsum(const int* __restrict__ bsum,
                                                  int* __restrict__ boff) {
    const int t = threadIdx.x;
    __shared__ int tmp[128];
    int v = (t < NB) ? bsum[t] : 0;
    tmp[t] = v;
    __syncthreads();
    for (int o = 1; o < 128; o <<= 1) {
        int y = (t >= o) ? tmp[t - o] : 0;
        __syncthreads();
        tmp[t] += y;
        __syncthreads();
    }
    if (t < NB) boff[t] = tmp[t] - v;   // exclusive
}

// Pass C: final exclusive scan -> rowptr, fillcur
__global__ __launch_bounds__(256) void k_scanfinal(const int* __restrict__ degi,
                                                   const int* __restrict__ boff,
                                                   int* __restrict__ rowptr,
                                                   int* __restrict__ fillcur) {
    const int t = threadIdx.x, b = blockIdx.x;
    const int lane = t & 63, wid = t >> 6;
    long i0 = (long)b * 1024 + t * 4;
    int d[4];
    #pragma unroll
    for (int u = 0; u < 4; ++u) { long i = i0 + u; d[u] = (i < N) ? degi[i] : 0; }
    int tsum = d[0] + d[1] + d[2] + d[3];
    int incl = tsum;
    #pragma unroll
    for (int o = 1; o < 64; o <<= 1) {
        int y = __shfl_up(incl, o);
        if (lane >= o) incl += y;
    }
    __shared__ int wsum[4];
    if (lane == 63) wsum[wid] = incl;
    __syncthreads();
    int wbase = 0;
    for (int w = 0; w < 4; ++w) if (w < wid) wbase += wsum[w];
    int base = boff[b] + wbase + (incl - tsum);
    int run = base;
    #pragma unroll
    for (int u = 0; u < 4; ++u) {
        long i = i0 + u;
        if (i < N) { rowptr[i] = run; fillcur[i] = run; }
        run += d[u];
    }
}

__global__ __launch_bounds__(256) void k_dinv(const int* __restrict__ degi,
                                              float* __restrict__ dinv) {
    int i = blockIdx.x * blockDim.x + threadIdx.x;
    if (i < N) dinv[i] = rsqrtf((float)degi[i] + 1.0f);   // +1 self loop
}

// range-partitioned fill: writes to colidx confined to ~1.6 MB window per range
__global__ __launch_bounds__(256) void k_fill(const int* __restrict__ src,
                                              const int* __restrict__ dst,
                                              int* __restrict__ fillcur,
                                              int* __restrict__ colidx) {
    const int r  = blockIdx.x % NRANGE;
    const int s  = blockIdx.x / NRANGE;
    const int lo = r * RSPAN, hi = min(N, lo + RSPAN);
    long e0 = (long)s * ESLICE;
    long e1 = min((long)E, e0 + ESLICE);
    for (long e = e0 + threadIdx.x; e < e1; e += 256) {
        int d = dst[e];
        if (d >= lo && d < hi) {
            int pos = atomicAdd(&fillcur[d], 1);
            colidx[pos] = src[e];
        }
    }
}

// ---------------- compute ----------------

// h1[i][j] = dinv[i] * sum_k x[i][k] * W1[k][j]
// 64 rows/block, 256 threads: r = t>>2 (row), g = t&3 (16-wide j group).
__global__ __launch_bounds__(256, 2) void k_gemm1(const float* __restrict__ x,
                                                  const float* __restrict__ W1,
                                                  const float* __restrict__ dinv,
                                                  float* __restrict__ h1) {
    __shared__ float xs[64][XS_LD];     // 33 KB, padded vs bank conflicts
    __shared__ float Ws[F_IN][WS_LD];   // 32 KB, j padded to 64
    const int t = threadIdx.x;
    const int row0 = blockIdx.x * 64;

    // stage W1 [128][50] -> Ws [128][64]
    for (int i = t; i < F_IN * H; i += 256)
        Ws[i / H][i % H] = W1[i];
    for (int i = t; i < F_IN * (WS_LD - H); i += 256)
        Ws[i / (WS_LD - H)][H + i % (WS_LD - H)] = 0.0f;
    // stage x rows as float4 (coalesced)
    for (int i = t; i < 64 * (F_IN / 4); i += 256) {
        int r  = i >> 5;          // /32 float4s per row
        int c4 = i & 31;
        int gr = row0 + r;
        float4 v = make_float4(0.f, 0.f, 0.f, 0.f);
        if (gr < N) v = *(const float4*)(x + (long)gr * F_IN + c4 * 4);
        *(float4*)&xs[r][c4 * 4] = v;
    }
    __syncthreads();

    const int r  = t >> 2;
    const int g  = t & 3;
    const int j0 = g * 16;
    float acc[16];
    #pragma unroll
    for (int u = 0; u < 16; ++u) acc[u] = 0.0f;

    const float* xrow = &xs[r][0];
    #pragma unroll 4
    for (int k0 = 0; k0 < F_IN; k0 += 4) {
        float4 xv = *(const float4*)(xrow + k0);
        float xk[4] = {xv.x, xv.y, xv.z, xv.w};
        #pragma unroll
        for (int kk = 0; kk < 4; ++kk) {
            const float* wrow = &Ws[k0 + kk][j0];
            float4 wa = *(const float4*)(wrow);
            float4 wb = *(const float4*)(wrow + 4);
            float4 wc = *(const float4*)(wrow + 8);
            float4 wd = *(const float4*)(wrow + 12);
            float xr = xk[kk];
            acc[0]  += xr * wa.x; acc[1]  += xr * wa.y;
            acc[2]  += xr * wa.z; acc[3]  += xr * wa.w;
            acc[4]  += xr * wb.x; acc[5]  += xr * wb.y;
            acc[6]  += xr * wb.z; acc[7]  += xr * wb.w;
            acc[8]  += xr * wc.x; acc[9]  += xr * wc.y;
            acc[10] += xr * wc.z; acc[11] += xr * wc.w;
            acc[12] += xr * wd.x; acc[13] += xr * wd.y;
            acc[14] += xr * wd.z; acc[15] += xr * wd.w;
        }
    }

    int gr = row0 + r;
    if (gr >= N) return;
    float di = dinv[gr];
    #pragma unroll
    for (int u = 0; u < 16; ++u) {
        int j = j0 + u;
        if (j < H) h1[(long)gr * H + j] = di * acc[u];
    }
}

// wave-per-node: agg1 = self + sum_{nbr} h1[nbr]; z1 = relu(di*agg1+b1);
// h2[i] = di * (z1 @ W2)
__global__ __launch_bounds__(256) void k_agg1_fused(const int* __restrict__ rowptr,
                                                    const int* __restrict__ degi,
                                                    const int* __restrict__ colidx,
                                                    const float* __restrict__ h1,
                                                    const float* __restrict__ dinv,
                                                    const float* __restrict__ b1,
                                                    const float* __restrict__ W2,
                                                    float* __restrict__ h2) {
    const int lane = threadIdx.x & 63;
    const bool act = lane < H;
    float b1v = act ? b1[lane] : 0.0f;
    float w20 = act ? W2[lane * 2 + 0] : 0.0f;
    float w21 = act ? W2[lane * 2 + 1] : 0.0f;

    long gw = ((long)blockIdx.x * blockDim.x + threadIdx.x) >> 6;
    long nw = ((long)gridDim.x * blockDim.x) >> 6;
    for (long i = gw; i < N; i += nw) {
        const int start = rowptr[i];
        const int deg   = degi[i];
        float a0 = act ? h1[i * (long)H + lane] : 0.0f;   // self loop
        float a1 = 0.0f, a2 = 0.0f, a3 = 0.0f;
        int k = 0;
        for (; k + 4 <= deg; k += 4) {
            int s0 = colidx[start + k + 0];
            int s1 = colidx[start + k + 1];
            int s2 = colidx[start + k + 2];
            int s3 = colidx[start + k + 3];
            if (act) {
                a0 += h1[(long)s0 * H + lane];
                a1 += h1[(long)s1 * H + lane];
                a2 += h1[(long)s2 * H + lane];
                a3 += h1[(long)s3 * H + lane];
            }
        }
        for (; k < deg; ++k) {
            int s = colidx[start + k];
            if (act) a0 += h1[(long)s * H + lane];
        }
        float agg = (a0 + a1) + (a2 + a3);
        float di = dinv[i];
        float v = fmaxf(di * agg + b1v, 0.0f);
        float p0 = v * w20, p1 = v * w21;
        #pragma unroll
        for (int o = 32; o > 0; o >>= 1) {
            p0 += __shfl_xor(p0, o);
            p1 += __shfl_xor(p1, o);
        }
        if (lane == 0) {
            h2[i * 2 + 0] = di * p0;
            h2[i * 2 + 1] = di * p1;
        }
    }
}

// wave-per-node, lanes over edges: out = log_softmax(di*(sum+self)+b2)
__global__ __launch_bounds__(256) void k_agg2_final(const int* __restrict__ rowptr,
                                                    const int* __restrict__ degi,
                                                    const int* __restrict__ colidx,
                                                    const float* __restrict__ h2,
                                                    const float* __restrict__ dinv,
                                                    const float* __restrict__ b2,
                                                    float* __restrict__ out) {
    const int lane = threadIdx.x & 63;
    long gw = ((long)blockIdx.x * blockDim.x + threadIdx.x) >> 6;
    long nw = ((long)gridDim.x * blockDim.x) >> 6;
    for (long i = gw; i < N; i += nw) {
        const int start = rowptr[i];
        const int deg   = degi[i];
        float s0 = 0.0f, s1 = 0.0f;
        for (int k = lane; k < deg; k += 64) {
            int s = colidx[start + k];
            s0 += h2[(long)s * 2 + 0];
            s1 += h2[(long)s * 2 + 1];
        }
        #pragma unroll
        for (int o = 32; o > 0; o >>= 1) {
            s0 += __shfl_xor(s0, o);
            s1 += __shfl_xor(s1, o);
        }
        if (lane == 0) {
            float di = dinv[i];
            float a0 = di * (s0 + h2[i * 2 + 0]) + b2[0];
            float a1 = di * (s1 + h2[i * 2 + 1]) + b2[1];
            float m = fmaxf(a0, a1);
            float lse = m + logf(expf(a0 - m) + expf(a1 - m));
            out[i * 2 + 0] = a0 - lse;
            out[i * 2 + 1] = a1 - lse;
        }
    }
}

extern "C" void kernel_launch(void* const* d_in, const int* in_sizes, int n_in,
                              void* d_out, int out_size, void* d_ws, size_t ws_size,
                              hipStream_t stream) {
    const float* x  = (const float*)d_in[0];
    const int*   ei = (const int*)d_in[1];   // [2][E]: row0 src, row1 dst
    const float* W1 = (const float*)d_in[2];
    const float* b1 = (const float*)d_in[3];
    const float* W2 = (const float*)d_in[4];
    const float* b2 = (const float*)d_in[5];
    float* out = (float*)d_out;

    const int* src = ei;
    const int* dst = ei + E;

    // ws layout
    int*   degi    = (int*)d_ws;            // N
    int*   rowptr  = degi + N;              // N
    int*   fillcur = rowptr + N;            // N
    int*   bsum    = fillcur + N;           // 128
    int*   boff    = bsum + 128;            // 128
    float* dinv    = (float*)(boff + 128);  // N
    int*   colidx  = (int*)(dinv + N);      // E
    float* h1      = (float*)(colidx + E);  // N*H
    float* h2      = h1 + (long)N * H;      // N*C   (~35 MB total)

    k_zero<<<(N + 255) / 256, 256, 0, stream>>>(degi);
    k_deg<<<NRANGE * NSLICE, 256, 0, stream>>>(dst, degi);
    k_blocksum<<<NB, 256, 0, stream>>>(degi, bsum);
    k_scanbsum<<<1, 128, 0, stream>>>(bsum, boff);
    k_scanfinal<<<NB, 256, 0, stream>>>(degi, boff, rowptr, fillcur);
    k_dinv<<<(N + 255) / 256, 256, 0, stream>>>(degi, dinv);
    k_fill<<<NRANGE * NSLICE, 256, 0, stream>>>(src, dst, fillcur, colidx);
    k_gemm1<<<(N + 63) / 64, 256, 0, stream>>>(x, W1, dinv, h1);
    k_agg1_fused<<<2048, 256, 0, stream>>>(rowptr, degi, colidx, h1, dinv, b1, W2, h2);
    k_agg2_final<<<2048, 256, 0, stream>>>(rowptr, degi, colidx, h2, dinv, b2, out);
}